// Round 10
// baseline (591.957 us; speedup 1.0000x reference)
//
#include <hip/hip_runtime.h>
#include <math.h>

#define HSZ 50000
#define INSZ 50000
#define NNZc 800000
#define BSZ 8
#define TSZ 32

#define CHUNK 2048
#define NBLK ((NNZc + CHUNK - 1) / CHUNK)    // 391
#define NCB 196                              // ceil(HSZ/256)
#define HWORDS (256 * NBLK)                  // 100096 per matrix
#define NC2 ((HWORDS + 1023) / 1024)         // 98

#define NPB 1024                             // cooperative blocks — PROVEN resident+launchable (R5 ran)
#define GRPS 8
#define GCNT (NPB / GRPS)                    // 128 arrivals per leaf
#define ROWS_SWEEP (NPB * 32)                // 32768 rows per sweep; 2 sweeps cover HSZ

typedef _Float16 half8 __attribute__((ext_vector_type(8)));
typedef _Float16 half4 __attribute__((ext_vector_type(4)));

__device__ __forceinline__ unsigned f2h_bits(float f) {
    _Float16 h = (_Float16)f;
    unsigned short u;
    __builtin_memcpy(&u, &h, 2);
    return (unsigned)u;
}
__device__ __forceinline__ float h_bits2f(unsigned u) {
    unsigned short us = (unsigned short)u;
    _Float16 h;
    __builtin_memcpy(&h, &us, 2);
    return (float)h;
}

// ---------------- CSR build: atomic-free radix partition on row>>8 ----------------

__global__ void p1_count(const int* __restrict__ hh_idx, const int* __restrict__ ih_idx,
                         int* __restrict__ ghist) {
    const int* rows = blockIdx.y ? ih_idx : hh_idx;
    __shared__ int cnt[256];
    int tid = threadIdx.x;
    cnt[tid] = 0;
    __syncthreads();
    int base = blockIdx.x * CHUNK;
    int nElem = min(CHUNK, NNZc - base);
    for (int k = tid; k < nElem; k += 256) {
        atomicAdd(&cnt[rows[base + k] >> 8], 1);
    }
    __syncthreads();
    ghist[((size_t)blockIdx.y * 256 + tid) * NBLK + blockIdx.x] = cnt[tid];
}

__global__ void p2scanA(int* __restrict__ ghist, int* __restrict__ partials) {
    int* g = ghist + (size_t)blockIdx.y * HWORDS;
    __shared__ int sm[1024];
    int tid = threadIdx.x;
    int idx = blockIdx.x * 1024 + tid;
    int v = (idx < HWORDS) ? g[idx] : 0;
    sm[tid] = v;
    __syncthreads();
    int x = v;
    for (int off = 1; off < 1024; off <<= 1) {
        int y = (tid >= off) ? sm[tid - off] : 0;
        __syncthreads();
        x += y;
        sm[tid] = x;
        __syncthreads();
    }
    if (idx < HWORDS) g[idx] = x - v;
    if (tid == 1023) partials[blockIdx.y * 128 + blockIdx.x] = x;
}

__global__ void p2scanB(int* __restrict__ partials) {
    __shared__ int sm[128];
    int tid = threadIdx.x;
    for (int m = 0; m < 2; ++m) {
        int v = (tid < NC2) ? partials[m * 128 + tid] : 0;
        sm[tid] = v;
        __syncthreads();
        int x = v;
        for (int off = 1; off < 128; off <<= 1) {
            int y = (tid >= off) ? sm[tid - off] : 0;
            __syncthreads();
            x += y;
            sm[tid] = x;
            __syncthreads();
        }
        if (tid < NC2) partials[m * 128 + tid] = x - v;
        __syncthreads();
    }
}

__global__ void p2scanC(int* __restrict__ ghist, const int* __restrict__ partials,
                        int* __restrict__ cbs) {
    int mat = blockIdx.y;
    int* g = ghist + (size_t)mat * HWORDS;
    int i = blockIdx.x * 256 + threadIdx.x;
    if (i < HWORDS) {
        int v = g[i] + partials[mat * 128 + (i >> 10)];
        g[i] = v;
        int b = i / NBLK;
        if (i - b * NBLK == 0 && b < NCB) cbs[mat * (NCB + 1) + b] = v;
    }
    if (i == 0) cbs[mat * (NCB + 1) + NCB] = NNZc;
}

__global__ void p2_part(const int* __restrict__ hh_idx, const float* __restrict__ hh_v,
                        const int* __restrict__ ih_idx, const float* __restrict__ ih_v,
                        const int* __restrict__ ghist,
                        uint2* __restrict__ tmp_hh, uint2* __restrict__ tmp_ih) {
    int mat = blockIdx.y;
    const int* idx = mat ? ih_idx : hh_idx;
    const float* val = mat ? ih_v : hh_v;
    uint2* tmp = mat ? tmp_ih : tmp_hh;
    const int* g = ghist + (size_t)mat * HWORDS;

    __shared__ int cnt[256];
    __shared__ int lstart[256];
    __shared__ int scanbuf[256];
    __shared__ int gbase[256];
    __shared__ uint2 stage[CHUNK];

    int tid = threadIdx.x;
    int base = blockIdx.x * CHUNK;
    int nElem = min(CHUNK, NNZc - base);

    cnt[tid] = 0;
    gbase[tid] = g[(size_t)tid * NBLK + blockIdx.x];
    __syncthreads();
    for (int k = tid; k < nElem; k += 256) {
        atomicAdd(&cnt[idx[base + k] >> 8], 1);
    }
    __syncthreads();
    int v = cnt[tid];
    scanbuf[tid] = v;
    __syncthreads();
    int x = v;
    for (int off = 1; off < 256; off <<= 1) {
        int y = (tid >= off) ? scanbuf[tid - off] : 0;
        __syncthreads();
        x += y;
        scanbuf[tid] = x;
        __syncthreads();
    }
    lstart[tid] = x - v;
    cnt[tid] = 0;
    __syncthreads();
    for (int k = tid; k < nElem; k += 256) {
        int r = idx[base + k];
        int c = idx[NNZc + base + k];
        int b = r >> 8;
        int rank = atomicAdd(&cnt[b], 1);
        stage[lstart[b] + rank] = make_uint2(((unsigned)r << 16) | (unsigned)c,
                                             __float_as_uint(val[base + k]));
    }
    __syncthreads();
    for (int k = tid; k < nElem; k += 256) {
        uint2 el = stage[k];
        int b = el.x >> 24;
        tmp[gbase[b] + (k - lstart[b])] = el;
    }
}

__global__ void p3_final(const int* __restrict__ cbs,
                         const uint2* __restrict__ tmp_hh, const uint2* __restrict__ tmp_ih,
                         int* __restrict__ ptr_hh, int* __restrict__ ptr_ih,
                         unsigned* __restrict__ cv_hh, unsigned* __restrict__ cv_ih) {
    int mat = blockIdx.y;
    const uint2* tmp = mat ? tmp_ih : tmp_hh;
    int* ptr = mat ? ptr_ih : ptr_hh;
    unsigned* cv = mat ? cv_ih : cv_hh;
    __shared__ int rcnt[256];
    __shared__ int rstart[256];
    __shared__ int scanbuf[256];
    int cb = blockIdx.x;
    int row0 = cb << 8;
    int nrows = min(256, HSZ - row0);
    int s = cbs[mat * (NCB + 1) + cb];
    int e = cbs[mat * (NCB + 1) + cb + 1];
    int tid = threadIdx.x;
    rcnt[tid] = 0;
    __syncthreads();
    for (int k = s + tid; k < e; k += 256) {
        atomicAdd(&rcnt[(tmp[k].x >> 16) & 255], 1);
    }
    __syncthreads();
    int v = rcnt[tid];
    scanbuf[tid] = v;
    __syncthreads();
    int x = v;
    for (int off = 1; off < 256; off <<= 1) {
        int y = (tid >= off) ? scanbuf[tid - off] : 0;
        __syncthreads();
        x += y;
        scanbuf[tid] = x;
        __syncthreads();
    }
    rstart[tid] = x - v;
    if (tid < nrows) ptr[row0 + tid] = s + x - v;
    if (cb == NCB - 1 && tid == 0) ptr[HSZ] = NNZc;
    rcnt[tid] = 0;
    __syncthreads();
    for (int k = s + tid; k < e; k += 256) {
        uint2 el = tmp[k];
        int lr = (el.x >> 16) & 255;
        int rank = atomicAdd(&rcnt[lr], 1);
        cv[s + rstart[lr] + rank] =
            (f2h_bits(__uint_as_float(el.y)) << 16) | (el.x & 0xffffu);
    }
}

// ---------------- transpose: x (B,T,IN) -> X2h (IN, 256) fp16, col = t*8+b ----------------

__global__ void transpose_x2(const float* __restrict__ x, _Float16* __restrict__ X2h) {
    extern __shared__ float tile[];   // 64 * 257 floats
    int i0 = blockIdx.x * 64;
    int tid = threadIdx.x;
    int il = tid & 15;
    int tr = (tid >> 4) & 3;
    int tg = tid >> 6;
#pragma unroll
    for (int iter = 0; iter < 16; ++iter) {
        int tb = iter * 16 + tg * 4 + tr;
        int t = tb >> 3, b = tb & 7;
        const float4 v = *reinterpret_cast<const float4*>(
            x + ((size_t)b * TSZ + t) * INSZ + i0 + il * 4);
        tile[(il * 4 + 0) * 257 + tb] = v.x;
        tile[(il * 4 + 1) * 257 + tb] = v.y;
        tile[(il * 4 + 2) * 257 + tb] = v.z;
        tile[(il * 4 + 3) * 257 + tb] = v.w;
    }
    __syncthreads();
    for (int k = 0; k < 64; ++k) {
        int i = i0 + k;
        if (i < INSZ) X2h[(size_t)i * 256 + tid] = (_Float16)tile[k * 257 + tid];
    }
}

// ---------------- ihc v5: one wave per row, 4-deep gather pipeline (fabric-BW floor) ----------------

__global__ void ihc_kernel(const int* __restrict__ ptr, const unsigned* __restrict__ cv,
                           const float* __restrict__ bias, const half4* __restrict__ X2h,
                           half4* __restrict__ ihcT) {
    __shared__ half4 lds[4 * 65];
    int wid = threadIdx.x >> 6;
    int lane = threadIdx.x & 63;
    int r = (blockIdx.x << 2) + wid;
    int s = ptr[r], e = ptr[r + 1];
    s = __builtin_amdgcn_readfirstlane(s);
    e = __builtin_amdgcn_readfirstlane(e);
    float4 acc = make_float4(0.f, 0.f, 0.f, 0.f);
    int j = s;
    for (; j + 3 < e; j += 4) {
        unsigned a = cv[j], b = cv[j + 1], c = cv[j + 2], d = cv[j + 3];
        float va = h_bits2f(a >> 16);
        float vb = h_bits2f(b >> 16);
        float vc = h_bits2f(c >> 16);
        float vd = h_bits2f(d >> 16);
        half4 x0 = X2h[((size_t)(a & 0xffffu) << 6) + lane];
        half4 x1 = X2h[((size_t)(b & 0xffffu) << 6) + lane];
        half4 x2 = X2h[((size_t)(c & 0xffffu) << 6) + lane];
        half4 x3 = X2h[((size_t)(d & 0xffffu) << 6) + lane];
        acc.x = fmaf(va, (float)x0[0], acc.x);
        acc.y = fmaf(va, (float)x0[1], acc.y);
        acc.z = fmaf(va, (float)x0[2], acc.z);
        acc.w = fmaf(va, (float)x0[3], acc.w);
        acc.x = fmaf(vb, (float)x1[0], acc.x);
        acc.y = fmaf(vb, (float)x1[1], acc.y);
        acc.z = fmaf(vb, (float)x1[2], acc.z);
        acc.w = fmaf(vb, (float)x1[3], acc.w);
        acc.x = fmaf(vc, (float)x2[0], acc.x);
        acc.y = fmaf(vc, (float)x2[1], acc.y);
        acc.z = fmaf(vc, (float)x2[2], acc.z);
        acc.w = fmaf(vc, (float)x2[3], acc.w);
        acc.x = fmaf(vd, (float)x3[0], acc.x);
        acc.y = fmaf(vd, (float)x3[1], acc.y);
        acc.z = fmaf(vd, (float)x3[2], acc.z);
        acc.w = fmaf(vd, (float)x3[3], acc.w);
    }
    for (; j < e; ++j) {
        unsigned a = cv[j];
        float va = h_bits2f(a >> 16);
        half4 x0 = X2h[((size_t)(a & 0xffffu) << 6) + lane];
        acc.x = fmaf(va, (float)x0[0], acc.x);
        acc.y = fmaf(va, (float)x0[1], acc.y);
        acc.z = fmaf(va, (float)x0[2], acc.z);
        acc.w = fmaf(va, (float)x0[3], acc.w);
    }
    float bb = bias[r];
    half4 o;
    o[0] = (_Float16)(acc.x + bb);
    o[1] = (_Float16)(acc.y + bb);
    o[2] = (_Float16)(acc.z + bb);
    o[3] = (_Float16)(acc.w + bb);
    lds[wid * 65 + lane] = o;
    __syncthreads();
    int plane = threadIdx.x >> 3;
    int w = threadIdx.x & 7;
    int row = w >> 1, q = w & 1;
    int r2 = (blockIdx.x << 2) + row;
    ihcT[((size_t)plane * HSZ + r2) * 2 + q] = lds[row * 65 + 2 * plane + q];
}

// ---------------- persistent recurrence v3 ----------------
// R5 (NPB=1024, atomic stores + ATOMIC gathers, flat barrier) RAN and was CORRECT but slow:
// bypass gathers = 102 MB/step fabric, flat barrier = 1024 contended RMWs on one line.
// R6 (NPB=1568) almost certainly failed at LAUNCH (coop-too-large, unchecked) -> out stayed
// zero -> absmax 0.996 == |tanh| max. This version: NPB=1024 (proven), PLAIN CACHED gathers
// (planes are write-once-then-read-once per launch; boundary L2 invalidation is proven by
// the per-launch chain's correctness), R5's proven write-through h-stores, tree barrier.

__device__ __forceinline__ float fast_tanh(float x) {
    float e = __expf(2.0f * x);
    return 1.0f - __fdividef(2.0f, e + 1.0f);
}

// ctl layout (ints): leaf[g*64 + t] (t<64), root[512 + t], rel[576 + g*64]
__device__ __forceinline__ void grid_bar(int* __restrict__ ctl, int t) {
    __syncthreads();   // drains vmcnt(0): this block's h write-through stores are at LLC
    if (threadIdx.x == 0) {
        int g = blockIdx.x & 7;
        __hip_atomic_fetch_add(&ctl[g * 64 + t], 1, __ATOMIC_RELAXED,
                               __HIP_MEMORY_SCOPE_AGENT);   // fire-and-forget arrival
        if (blockIdx.x < 8) {   // leader of group g == blockIdx.x
            while (__hip_atomic_load(&ctl[g * 64 + t], __ATOMIC_RELAXED,
                                     __HIP_MEMORY_SCOPE_AGENT) < GCNT)
                __builtin_amdgcn_s_sleep(1);
            __hip_atomic_fetch_add(&ctl[512 + t], 1, __ATOMIC_RELAXED,
                                   __HIP_MEMORY_SCOPE_AGENT);
            while (__hip_atomic_load(&ctl[512 + t], __ATOMIC_RELAXED,
                                     __HIP_MEMORY_SCOPE_AGENT) < GRPS)
                __builtin_amdgcn_s_sleep(1);
            __hip_atomic_store(&ctl[576 + g * 64], t + 1, __ATOMIC_RELAXED,
                               __HIP_MEMORY_SCOPE_AGENT);
        } else {
            while (__hip_atomic_load(&ctl[576 + g * 64], __ATOMIC_RELAXED,
                                     __HIP_MEMORY_SCOPE_AGENT) <= t)
                __builtin_amdgcn_s_sleep(2);
        }
    }
    __syncthreads();
}

__device__ __forceinline__ void do_row(int r, int s, int e, int t, int sub,
                                       const unsigned* __restrict__ cv,
                                       const half8* __restrict__ hprev,
                                       const half8* __restrict__ ihcT,
                                       unsigned long long* __restrict__ hw,
                                       float* __restrict__ out) {
    float a0 = 0.f, a1 = 0.f, a2 = 0.f, a3 = 0.f;
    float a4 = 0.f, a5 = 0.f, a6 = 0.f, a7 = 0.f;
    if (t > 0) {
        for (int j = s; j < e; j += 8) {
            unsigned u = cv[j];
            float v = h_bits2f(u >> 16);
            half8 hv = hprev[u & 0xffffu];        // plain cached load: first touch misses
            a0 = fmaf(v, (float)hv[0], a0);       // to LLC (holds write-through data),
            a1 = fmaf(v, (float)hv[1], a1);       // then L2-resident (16x line reuse)
            a2 = fmaf(v, (float)hv[2], a2);
            a3 = fmaf(v, (float)hv[3], a3);
            a4 = fmaf(v, (float)hv[4], a4);
            a5 = fmaf(v, (float)hv[5], a5);
            a6 = fmaf(v, (float)hv[6], a6);
            a7 = fmaf(v, (float)hv[7], a7);
        }
    }
    a0 += __shfl_xor(a0, 1); a1 += __shfl_xor(a1, 1);
    a2 += __shfl_xor(a2, 1); a3 += __shfl_xor(a3, 1);
    a4 += __shfl_xor(a4, 1); a5 += __shfl_xor(a5, 1);
    a6 += __shfl_xor(a6, 1); a7 += __shfl_xor(a7, 1);
    a0 += __shfl_xor(a0, 2); a1 += __shfl_xor(a1, 2);
    a2 += __shfl_xor(a2, 2); a3 += __shfl_xor(a3, 2);
    a4 += __shfl_xor(a4, 2); a5 += __shfl_xor(a5, 2);
    a6 += __shfl_xor(a6, 2); a7 += __shfl_xor(a7, 2);
    a0 += __shfl_xor(a0, 4); a1 += __shfl_xor(a1, 4);
    a2 += __shfl_xor(a2, 4); a3 += __shfl_xor(a3, 4);
    a4 += __shfl_xor(a4, 4); a5 += __shfl_xor(a5, 4);
    a6 += __shfl_xor(a6, 4); a7 += __shfl_xor(a7, 4);
    if (sub == 0) {
        half8 b8 = ihcT[(size_t)t * HSZ + r];
        float h0 = fast_tanh(a0 + (float)b8[0]);
        float h1 = fast_tanh(a1 + (float)b8[1]);
        float h2 = fast_tanh(a2 + (float)b8[2]);
        float h3 = fast_tanh(a3 + (float)b8[3]);
        float h4 = fast_tanh(a4 + (float)b8[4]);
        float h5 = fast_tanh(a5 + (float)b8[5]);
        float h6 = fast_tanh(a6 + (float)b8[6]);
        float h7 = fast_tanh(a7 + (float)b8[7]);
        half8 hh;
        hh[0] = (_Float16)h0; hh[1] = (_Float16)h1;
        hh[2] = (_Float16)h2; hh[3] = (_Float16)h3;
        hh[4] = (_Float16)h4; hh[5] = (_Float16)h5;
        hh[6] = (_Float16)h6; hh[7] = (_Float16)h7;
        union { half8 h; unsigned long long q[2]; } u2;
        u2.h = hh;
        __hip_atomic_store(hw + ((size_t)r << 1), u2.q[0], __ATOMIC_RELAXED,
                           __HIP_MEMORY_SCOPE_AGENT);       // write-through -> LLC (R5-proven)
        __hip_atomic_store(hw + ((size_t)r << 1) + 1, u2.q[1], __ATOMIC_RELAXED,
                           __HIP_MEMORY_SCOPE_AGENT);
        __builtin_nontemporal_store(h0, &out[((size_t)0 * TSZ + t) * HSZ + r]);
        __builtin_nontemporal_store(h1, &out[((size_t)1 * TSZ + t) * HSZ + r]);
        __builtin_nontemporal_store(h2, &out[((size_t)2 * TSZ + t) * HSZ + r]);
        __builtin_nontemporal_store(h3, &out[((size_t)3 * TSZ + t) * HSZ + r]);
        __builtin_nontemporal_store(h4, &out[((size_t)4 * TSZ + t) * HSZ + r]);
        __builtin_nontemporal_store(h5, &out[((size_t)5 * TSZ + t) * HSZ + r]);
        __builtin_nontemporal_store(h6, &out[((size_t)6 * TSZ + t) * HSZ + r]);
        __builtin_nontemporal_store(h7, &out[((size_t)7 * TSZ + t) * HSZ + r]);
    }
}

__global__ void __launch_bounds__(256, 4) steps_persist(
        const int* __restrict__ ptr, const unsigned* __restrict__ cv,
        const half8* __restrict__ ihcT, half8* __restrict__ hs,
        float* __restrict__ out, int* __restrict__ ctl) {
    int tid = threadIdx.x;
    int sub = tid & 7;
    int r0 = blockIdx.x * 32 + (tid >> 3);           // < 32768
    int r1 = r0 + ROWS_SWEEP;
    int s0 = ptr[r0] + sub, e0 = ptr[r0 + 1];        // hoisted: constant across t
    bool has1 = (r1 < HSZ);
    int s1 = 0, e1 = 0;
    if (has1) { s1 = ptr[r1] + sub; e1 = ptr[r1 + 1]; }

    for (int t = 0; t < TSZ; ++t) {
        const half8* __restrict__ hprev = hs + (size_t)(t > 0 ? t - 1 : 0) * HSZ;
        unsigned long long* __restrict__ hw =
            (unsigned long long*)(hs + (size_t)t * HSZ);
        do_row(r0, s0, e0, t, sub, cv, hprev, ihcT, hw, out);
        if (has1) do_row(r1, s1, e1, t, sub, cv, hprev, ihcT, hw, out);
        if (t < TSZ - 1) grid_bar(ctl, t);
    }
}

// ---------------- launch ----------------

static inline size_t align256(size_t x) { return (x + 255) & ~(size_t)255; }

extern "C" void kernel_launch(void* const* d_in, const int* in_sizes, int n_in,
                              void* d_out, int out_size, void* d_ws, size_t ws_size,
                              hipStream_t stream) {
    const float* x          = (const float*)d_in[0];
    const float* hh_values  = (const float*)d_in[1];
    const float* hh_bias    = (const float*)d_in[2];
    const float* ih_values  = (const float*)d_in[3];
    const int*   hh_indices = (const int*)d_in[4];
    const int*   ih_indices = (const int*)d_in[5];
    float* out = (float*)d_out;

    char* ws = (char*)d_ws;
    _Float16* X2h   = (_Float16*)ws; ws += align256((size_t)INSZ * 256 * 2);   // 25.6 MB
    half8*  hs      = (half8*)X2h;   // ALIAS: 32 planes x 800KB = 25.6MB reuse X2h.
                                     // Safe: X2h L2 copies invalidated at steps_persist
                                     // launch (boundary invalidation proven by per-launch
                                     // chain correctness); planes are write-once (step t,
                                     // through to LLC) then read-once (step t+1, first
                                     // touch must miss to LLC).
    half4*  ihcT    = (half4*)ws;  ws += align256((size_t)HSZ * 256 * 2);      // 25.6 MB
    int*    hh_ptr  = (int*)ws;    ws += align256((size_t)(HSZ + 1) * 4);
    int*    ih_ptr  = (int*)ws;    ws += align256((size_t)(HSZ + 1) * 4);
    int*    ghist   = (int*)ws;    ws += align256((size_t)2 * HWORDS * 4);     // 800 KB
    int*    partials= (int*)ws;    ws += align256((size_t)256 * 4);
    int*    cbs     = (int*)ws;    ws += align256((size_t)2 * (NCB + 1) * 4);
    int*    ctl     = (int*)ws;    ws += align256((size_t)1088 * 4);           // barrier tree
    uint2*  tmp_hh  = (uint2*)ws;  ws += align256((size_t)NNZc * 8);           // 6.4 MB
    uint2*  tmp_ih  = (uint2*)ws;  ws += align256((size_t)NNZc * 8);           // 6.4 MB
    unsigned* cv_hh = (unsigned*)ws; ws += align256((size_t)NNZc * 4);         // 3.2 MB
    unsigned* cv_ih = (unsigned*)ws; ws += align256((size_t)NNZc * 4);         // 3.2 MB

    hipMemsetAsync(ctl, 0, (size_t)1088 * 4, stream);   // fresh barrier counters per replay

    p1_count<<<dim3(NBLK, 2), 256, 0, stream>>>(hh_indices, ih_indices, ghist);
    p2scanA<<<dim3(NC2, 2), 1024, 0, stream>>>(ghist, partials);
    p2scanB<<<1, 128, 0, stream>>>(partials);
    p2scanC<<<dim3((HWORDS + 255) / 256, 2), 256, 0, stream>>>(ghist, partials, cbs);
    p2_part<<<dim3(NBLK, 2), 256, 0, stream>>>(hh_indices, hh_values, ih_indices, ih_values,
                                               ghist, tmp_hh, tmp_ih);
    p3_final<<<dim3(NCB, 2), 256, 0, stream>>>(cbs, tmp_hh, tmp_ih,
                                               hh_ptr, ih_ptr, cv_hh, cv_ih);

    transpose_x2<<<(INSZ + 63) / 64, 256, 64 * 257 * 4, stream>>>(x, X2h);
    ihc_kernel<<<HSZ / 4, 256, 0, stream>>>(ih_ptr, cv_ih, hh_bias, (const half4*)X2h, ihcT);

    {
        const int* a0 = hh_ptr;
        const unsigned* a1 = cv_hh;
        const half8* a2 = (const half8*)ihcT;
        half8* a3 = hs;
        float* a4 = out;
        int* a5 = ctl;
        void* args[] = {(void*)&a0, (void*)&a1, (void*)&a2, (void*)&a3,
                        (void*)&a4, (void*)&a5};
        hipLaunchCooperativeKernel(reinterpret_cast<void*>(steps_persist),
                                   dim3(NPB), dim3(256), args, 0, stream);
    }
}

// Round 11
// 553.061 us; speedup vs baseline: 1.0703x; 1.0703x over previous
//
#include <hip/hip_runtime.h>
#include <math.h>

#define HSZ 50000
#define INSZ 50000
#define NNZc 800000
#define BSZ 8
#define TSZ 32

#define CHUNK 2048
#define NBLK ((NNZc + CHUNK - 1) / CHUNK)    // 391
#define NCB 196                              // ceil(HSZ/256)
#define HWORDS (256 * NBLK)                  // 100096 per matrix
#define NC2 ((HWORDS + 1023) / 1024)         // 98

// Persistent-normal launch: 1008 blocks x (256 thr, 4 waves). __launch_bounds__(256,4)
// -> 16 waves/CU -> 4 blocks/CU -> capacity 1024 blocks on 256 CUs; 1008 leaves slack.
// All blocks are placed before any retires (none retire mid-kernel), so a NORMAL launch
// is co-resident by capacity arithmetic -- no cooperative API (R10 showed ~120us overhead).
#define NPB 1008
#define GRPS 8
#define GCNT (NPB / GRPS)                    // 126 arrivals per leaf
#define ROWS_SWEEP (NPB * 32)                // 32256 rows per sweep; 2 sweeps cover HSZ

typedef _Float16 half8 __attribute__((ext_vector_type(8)));
typedef _Float16 half4 __attribute__((ext_vector_type(4)));

__device__ __forceinline__ unsigned f2h_bits(float f) {
    _Float16 h = (_Float16)f;
    unsigned short u;
    __builtin_memcpy(&u, &h, 2);
    return (unsigned)u;
}
__device__ __forceinline__ float h_bits2f(unsigned u) {
    unsigned short us = (unsigned short)u;
    _Float16 h;
    __builtin_memcpy(&h, &us, 2);
    return (float)h;
}

// ---------------- CSR build: atomic-free radix partition on row>>8 ----------------

__global__ void p1_count(const int* __restrict__ hh_idx, const int* __restrict__ ih_idx,
                         int* __restrict__ ghist) {
    const int* rows = blockIdx.y ? ih_idx : hh_idx;
    __shared__ int cnt[256];
    int tid = threadIdx.x;
    cnt[tid] = 0;
    __syncthreads();
    int base = blockIdx.x * CHUNK;
    int nElem = min(CHUNK, NNZc - base);
    for (int k = tid; k < nElem; k += 256) {
        atomicAdd(&cnt[rows[base + k] >> 8], 1);
    }
    __syncthreads();
    ghist[((size_t)blockIdx.y * 256 + tid) * NBLK + blockIdx.x] = cnt[tid];
}

__global__ void p2scanA(int* __restrict__ ghist, int* __restrict__ partials) {
    int* g = ghist + (size_t)blockIdx.y * HWORDS;
    __shared__ int sm[1024];
    int tid = threadIdx.x;
    int idx = blockIdx.x * 1024 + tid;
    int v = (idx < HWORDS) ? g[idx] : 0;
    sm[tid] = v;
    __syncthreads();
    int x = v;
    for (int off = 1; off < 1024; off <<= 1) {
        int y = (tid >= off) ? sm[tid - off] : 0;
        __syncthreads();
        x += y;
        sm[tid] = x;
        __syncthreads();
    }
    if (idx < HWORDS) g[idx] = x - v;
    if (tid == 1023) partials[blockIdx.y * 128 + blockIdx.x] = x;
}

__global__ void p2scanB(int* __restrict__ partials) {
    __shared__ int sm[128];
    int tid = threadIdx.x;
    for (int m = 0; m < 2; ++m) {
        int v = (tid < NC2) ? partials[m * 128 + tid] : 0;
        sm[tid] = v;
        __syncthreads();
        int x = v;
        for (int off = 1; off < 128; off <<= 1) {
            int y = (tid >= off) ? sm[tid - off] : 0;
            __syncthreads();
            x += y;
            sm[tid] = x;
            __syncthreads();
        }
        if (tid < NC2) partials[m * 128 + tid] = x - v;
        __syncthreads();
    }
}

__global__ void p2scanC(int* __restrict__ ghist, const int* __restrict__ partials,
                        int* __restrict__ cbs) {
    int mat = blockIdx.y;
    int* g = ghist + (size_t)mat * HWORDS;
    int i = blockIdx.x * 256 + threadIdx.x;
    if (i < HWORDS) {
        int v = g[i] + partials[mat * 128 + (i >> 10)];
        g[i] = v;
        int b = i / NBLK;
        if (i - b * NBLK == 0 && b < NCB) cbs[mat * (NCB + 1) + b] = v;
    }
    if (i == 0) cbs[mat * (NCB + 1) + NCB] = NNZc;
}

__global__ void p2_part(const int* __restrict__ hh_idx, const float* __restrict__ hh_v,
                        const int* __restrict__ ih_idx, const float* __restrict__ ih_v,
                        const int* __restrict__ ghist,
                        uint2* __restrict__ tmp_hh, uint2* __restrict__ tmp_ih) {
    int mat = blockIdx.y;
    const int* idx = mat ? ih_idx : hh_idx;
    const float* val = mat ? ih_v : hh_v;
    uint2* tmp = mat ? tmp_ih : tmp_hh;
    const int* g = ghist + (size_t)mat * HWORDS;

    __shared__ int cnt[256];
    __shared__ int lstart[256];
    __shared__ int scanbuf[256];
    __shared__ int gbase[256];
    __shared__ uint2 stage[CHUNK];

    int tid = threadIdx.x;
    int base = blockIdx.x * CHUNK;
    int nElem = min(CHUNK, NNZc - base);

    cnt[tid] = 0;
    gbase[tid] = g[(size_t)tid * NBLK + blockIdx.x];
    __syncthreads();
    for (int k = tid; k < nElem; k += 256) {
        atomicAdd(&cnt[idx[base + k] >> 8], 1);
    }
    __syncthreads();
    int v = cnt[tid];
    scanbuf[tid] = v;
    __syncthreads();
    int x = v;
    for (int off = 1; off < 256; off <<= 1) {
        int y = (tid >= off) ? scanbuf[tid - off] : 0;
        __syncthreads();
        x += y;
        scanbuf[tid] = x;
        __syncthreads();
    }
    lstart[tid] = x - v;
    cnt[tid] = 0;
    __syncthreads();
    for (int k = tid; k < nElem; k += 256) {
        int r = idx[base + k];
        int c = idx[NNZc + base + k];
        int b = r >> 8;
        int rank = atomicAdd(&cnt[b], 1);
        stage[lstart[b] + rank] = make_uint2(((unsigned)r << 16) | (unsigned)c,
                                             __float_as_uint(val[base + k]));
    }
    __syncthreads();
    for (int k = tid; k < nElem; k += 256) {
        uint2 el = stage[k];
        int b = el.x >> 24;
        tmp[gbase[b] + (k - lstart[b])] = el;
    }
}

__global__ void p3_final(const int* __restrict__ cbs,
                         const uint2* __restrict__ tmp_hh, const uint2* __restrict__ tmp_ih,
                         int* __restrict__ ptr_hh, int* __restrict__ ptr_ih,
                         unsigned* __restrict__ cv_hh, unsigned* __restrict__ cv_ih) {
    int mat = blockIdx.y;
    const uint2* tmp = mat ? tmp_ih : tmp_hh;
    int* ptr = mat ? ptr_ih : ptr_hh;
    unsigned* cv = mat ? cv_ih : cv_hh;
    __shared__ int rcnt[256];
    __shared__ int rstart[256];
    __shared__ int scanbuf[256];
    int cb = blockIdx.x;
    int row0 = cb << 8;
    int nrows = min(256, HSZ - row0);
    int s = cbs[mat * (NCB + 1) + cb];
    int e = cbs[mat * (NCB + 1) + cb + 1];
    int tid = threadIdx.x;
    rcnt[tid] = 0;
    __syncthreads();
    for (int k = s + tid; k < e; k += 256) {
        atomicAdd(&rcnt[(tmp[k].x >> 16) & 255], 1);
    }
    __syncthreads();
    int v = rcnt[tid];
    scanbuf[tid] = v;
    __syncthreads();
    int x = v;
    for (int off = 1; off < 256; off <<= 1) {
        int y = (tid >= off) ? scanbuf[tid - off] : 0;
        __syncthreads();
        x += y;
        scanbuf[tid] = x;
        __syncthreads();
    }
    rstart[tid] = x - v;
    if (tid < nrows) ptr[row0 + tid] = s + x - v;
    if (cb == NCB - 1 && tid == 0) ptr[HSZ] = NNZc;
    rcnt[tid] = 0;
    __syncthreads();
    for (int k = s + tid; k < e; k += 256) {
        uint2 el = tmp[k];
        int lr = (el.x >> 16) & 255;
        int rank = atomicAdd(&rcnt[lr], 1);
        cv[s + rstart[lr] + rank] =
            (f2h_bits(__uint_as_float(el.y)) << 16) | (el.x & 0xffffu);
    }
}

// ---------------- transpose: x (B,T,IN) -> X2h (IN, 256) fp16, col = t*8+b ----------------

__global__ void transpose_x2(const float* __restrict__ x, _Float16* __restrict__ X2h) {
    extern __shared__ float tile[];   // 64 * 257 floats
    int i0 = blockIdx.x * 64;
    int tid = threadIdx.x;
    int il = tid & 15;
    int tr = (tid >> 4) & 3;
    int tg = tid >> 6;
#pragma unroll
    for (int iter = 0; iter < 16; ++iter) {
        int tb = iter * 16 + tg * 4 + tr;
        int t = tb >> 3, b = tb & 7;
        const float4 v = *reinterpret_cast<const float4*>(
            x + ((size_t)b * TSZ + t) * INSZ + i0 + il * 4);
        tile[(il * 4 + 0) * 257 + tb] = v.x;
        tile[(il * 4 + 1) * 257 + tb] = v.y;
        tile[(il * 4 + 2) * 257 + tb] = v.z;
        tile[(il * 4 + 3) * 257 + tb] = v.w;
    }
    __syncthreads();
    for (int k = 0; k < 64; ++k) {
        int i = i0 + k;
        if (i < INSZ) X2h[(size_t)i * 256 + tid] = (_Float16)tile[k * 257 + tid];
    }
}

// ---------------- ihc v5: one wave per row, 4-deep gather pipeline (fabric-BW floor) ----------------

__global__ void ihc_kernel(const int* __restrict__ ptr, const unsigned* __restrict__ cv,
                           const float* __restrict__ bias, const half4* __restrict__ X2h,
                           half4* __restrict__ ihcT) {
    __shared__ half4 lds[4 * 65];
    int wid = threadIdx.x >> 6;
    int lane = threadIdx.x & 63;
    int r = (blockIdx.x << 2) + wid;
    int s = ptr[r], e = ptr[r + 1];
    s = __builtin_amdgcn_readfirstlane(s);
    e = __builtin_amdgcn_readfirstlane(e);
    float4 acc = make_float4(0.f, 0.f, 0.f, 0.f);
    int j = s;
    for (; j + 3 < e; j += 4) {
        unsigned a = cv[j], b = cv[j + 1], c = cv[j + 2], d = cv[j + 3];
        float va = h_bits2f(a >> 16);
        float vb = h_bits2f(b >> 16);
        float vc = h_bits2f(c >> 16);
        float vd = h_bits2f(d >> 16);
        half4 x0 = X2h[((size_t)(a & 0xffffu) << 6) + lane];
        half4 x1 = X2h[((size_t)(b & 0xffffu) << 6) + lane];
        half4 x2 = X2h[((size_t)(c & 0xffffu) << 6) + lane];
        half4 x3 = X2h[((size_t)(d & 0xffffu) << 6) + lane];
        acc.x = fmaf(va, (float)x0[0], acc.x);
        acc.y = fmaf(va, (float)x0[1], acc.y);
        acc.z = fmaf(va, (float)x0[2], acc.z);
        acc.w = fmaf(va, (float)x0[3], acc.w);
        acc.x = fmaf(vb, (float)x1[0], acc.x);
        acc.y = fmaf(vb, (float)x1[1], acc.y);
        acc.z = fmaf(vb, (float)x1[2], acc.z);
        acc.w = fmaf(vb, (float)x1[3], acc.w);
        acc.x = fmaf(vc, (float)x2[0], acc.x);
        acc.y = fmaf(vc, (float)x2[1], acc.y);
        acc.z = fmaf(vc, (float)x2[2], acc.z);
        acc.w = fmaf(vc, (float)x2[3], acc.w);
        acc.x = fmaf(vd, (float)x3[0], acc.x);
        acc.y = fmaf(vd, (float)x3[1], acc.y);
        acc.z = fmaf(vd, (float)x3[2], acc.z);
        acc.w = fmaf(vd, (float)x3[3], acc.w);
    }
    for (; j < e; ++j) {
        unsigned a = cv[j];
        float va = h_bits2f(a >> 16);
        half4 x0 = X2h[((size_t)(a & 0xffffu) << 6) + lane];
        acc.x = fmaf(va, (float)x0[0], acc.x);
        acc.y = fmaf(va, (float)x0[1], acc.y);
        acc.z = fmaf(va, (float)x0[2], acc.z);
        acc.w = fmaf(va, (float)x0[3], acc.w);
    }
    float bb = bias[r];
    half4 o;
    o[0] = (_Float16)(acc.x + bb);
    o[1] = (_Float16)(acc.y + bb);
    o[2] = (_Float16)(acc.z + bb);
    o[3] = (_Float16)(acc.w + bb);
    lds[wid * 65 + lane] = o;
    __syncthreads();
    int plane = threadIdx.x >> 3;
    int w = threadIdx.x & 7;
    int row = w >> 1, q = w & 1;
    int r2 = (blockIdx.x << 2) + row;
    ihcT[((size_t)plane * HSZ + r2) * 2 + q] = lds[row * 65 + 2 * plane + q];
}

// ---------------- persistent recurrence v4: NORMAL launch (no coop API) ----------------
// R10 proved this exact scheme correct (cached gathers + write-through h + tree barrier)
// at 350us for all 32 steps, but total regressed ~120us -- suspected coop-launch/graph
// interaction. Same kernel, plain launch; co-residency by capacity (see NPB comment).

__device__ __forceinline__ float fast_tanh(float x) {
    float e = __expf(2.0f * x);
    return 1.0f - __fdividef(2.0f, e + 1.0f);
}

// ctl layout (ints): leaf[g*64 + t], root[512 + t], rel[576 + g*64]
__device__ __forceinline__ void grid_bar(int* __restrict__ ctl, int t) {
    __syncthreads();   // drains vmcnt(0): this block's h write-through stores are at LLC
    if (threadIdx.x == 0) {
        int g = blockIdx.x & 7;
        __hip_atomic_fetch_add(&ctl[g * 64 + t], 1, __ATOMIC_RELAXED,
                               __HIP_MEMORY_SCOPE_AGENT);   // fire-and-forget arrival
        if (blockIdx.x < 8) {   // leader of group g == blockIdx.x
            while (__hip_atomic_load(&ctl[g * 64 + t], __ATOMIC_RELAXED,
                                     __HIP_MEMORY_SCOPE_AGENT) < GCNT)
                __builtin_amdgcn_s_sleep(1);
            __hip_atomic_fetch_add(&ctl[512 + t], 1, __ATOMIC_RELAXED,
                                   __HIP_MEMORY_SCOPE_AGENT);
            while (__hip_atomic_load(&ctl[512 + t], __ATOMIC_RELAXED,
                                     __HIP_MEMORY_SCOPE_AGENT) < GRPS)
                __builtin_amdgcn_s_sleep(1);
            __hip_atomic_store(&ctl[576 + g * 64], t + 1, __ATOMIC_RELAXED,
                               __HIP_MEMORY_SCOPE_AGENT);
        } else {
            // longer sleep: ~1000 spinners polling 8 LLC lines -- cut the poll storm
            while (__hip_atomic_load(&ctl[576 + g * 64], __ATOMIC_RELAXED,
                                     __HIP_MEMORY_SCOPE_AGENT) <= t)
                __builtin_amdgcn_s_sleep(8);
        }
    }
    __syncthreads();
}

__device__ __forceinline__ void do_row(int r, int s, int e, int t, int sub,
                                       const unsigned* __restrict__ cv,
                                       const half8* __restrict__ hprev,
                                       const half8* __restrict__ ihcT,
                                       unsigned long long* __restrict__ hw,
                                       float* __restrict__ out) {
    float a0 = 0.f, a1 = 0.f, a2 = 0.f, a3 = 0.f;
    float a4 = 0.f, a5 = 0.f, a6 = 0.f, a7 = 0.f;
    if (t > 0) {
        for (int j = s; j < e; j += 8) {
            unsigned u = cv[j];
            float v = h_bits2f(u >> 16);
            half8 hv = hprev[u & 0xffffu];        // plain cached load (R10-proven correct)
            a0 = fmaf(v, (float)hv[0], a0);
            a1 = fmaf(v, (float)hv[1], a1);
            a2 = fmaf(v, (float)hv[2], a2);
            a3 = fmaf(v, (float)hv[3], a3);
            a4 = fmaf(v, (float)hv[4], a4);
            a5 = fmaf(v, (float)hv[5], a5);
            a6 = fmaf(v, (float)hv[6], a6);
            a7 = fmaf(v, (float)hv[7], a7);
        }
    }
    a0 += __shfl_xor(a0, 1); a1 += __shfl_xor(a1, 1);
    a2 += __shfl_xor(a2, 1); a3 += __shfl_xor(a3, 1);
    a4 += __shfl_xor(a4, 1); a5 += __shfl_xor(a5, 1);
    a6 += __shfl_xor(a6, 1); a7 += __shfl_xor(a7, 1);
    a0 += __shfl_xor(a0, 2); a1 += __shfl_xor(a1, 2);
    a2 += __shfl_xor(a2, 2); a3 += __shfl_xor(a3, 2);
    a4 += __shfl_xor(a4, 2); a5 += __shfl_xor(a5, 2);
    a6 += __shfl_xor(a6, 2); a7 += __shfl_xor(a7, 2);
    a0 += __shfl_xor(a0, 4); a1 += __shfl_xor(a1, 4);
    a2 += __shfl_xor(a2, 4); a3 += __shfl_xor(a3, 4);
    a4 += __shfl_xor(a4, 4); a5 += __shfl_xor(a5, 4);
    a6 += __shfl_xor(a6, 4); a7 += __shfl_xor(a7, 4);
    if (sub == 0) {
        half8 b8 = ihcT[(size_t)t * HSZ + r];
        float h0 = fast_tanh(a0 + (float)b8[0]);
        float h1 = fast_tanh(a1 + (float)b8[1]);
        float h2 = fast_tanh(a2 + (float)b8[2]);
        float h3 = fast_tanh(a3 + (float)b8[3]);
        float h4 = fast_tanh(a4 + (float)b8[4]);
        float h5 = fast_tanh(a5 + (float)b8[5]);
        float h6 = fast_tanh(a6 + (float)b8[6]);
        float h7 = fast_tanh(a7 + (float)b8[7]);
        half8 hh;
        hh[0] = (_Float16)h0; hh[1] = (_Float16)h1;
        hh[2] = (_Float16)h2; hh[3] = (_Float16)h3;
        hh[4] = (_Float16)h4; hh[5] = (_Float16)h5;
        hh[6] = (_Float16)h6; hh[7] = (_Float16)h7;
        union { half8 h; unsigned long long q[2]; } u2;
        u2.h = hh;
        __hip_atomic_store(hw + ((size_t)r << 1), u2.q[0], __ATOMIC_RELAXED,
                           __HIP_MEMORY_SCOPE_AGENT);       // write-through -> LLC
        __hip_atomic_store(hw + ((size_t)r << 1) + 1, u2.q[1], __ATOMIC_RELAXED,
                           __HIP_MEMORY_SCOPE_AGENT);
        __builtin_nontemporal_store(h0, &out[((size_t)0 * TSZ + t) * HSZ + r]);
        __builtin_nontemporal_store(h1, &out[((size_t)1 * TSZ + t) * HSZ + r]);
        __builtin_nontemporal_store(h2, &out[((size_t)2 * TSZ + t) * HSZ + r]);
        __builtin_nontemporal_store(h3, &out[((size_t)3 * TSZ + t) * HSZ + r]);
        __builtin_nontemporal_store(h4, &out[((size_t)4 * TSZ + t) * HSZ + r]);
        __builtin_nontemporal_store(h5, &out[((size_t)5 * TSZ + t) * HSZ + r]);
        __builtin_nontemporal_store(h6, &out[((size_t)6 * TSZ + t) * HSZ + r]);
        __builtin_nontemporal_store(h7, &out[((size_t)7 * TSZ + t) * HSZ + r]);
    }
}

__global__ void __launch_bounds__(256, 4) steps_persist(
        const int* __restrict__ ptr, const unsigned* __restrict__ cv,
        const half8* __restrict__ ihcT, half8* __restrict__ hs,
        float* __restrict__ out, int* __restrict__ ctl) {
    int tid = threadIdx.x;
    int sub = tid & 7;
    int r0 = blockIdx.x * 32 + (tid >> 3);           // < 32256
    int r1 = r0 + ROWS_SWEEP;
    int s0 = ptr[r0] + sub, e0 = ptr[r0 + 1];        // hoisted: constant across t
    bool has1 = (r1 < HSZ);
    int s1 = 0, e1 = 0;
    if (has1) { s1 = ptr[r1] + sub; e1 = ptr[r1 + 1]; }

    for (int t = 0; t < TSZ; ++t) {
        const half8* __restrict__ hprev = hs + (size_t)(t > 0 ? t - 1 : 0) * HSZ;
        unsigned long long* __restrict__ hw =
            (unsigned long long*)(hs + (size_t)t * HSZ);
        do_row(r0, s0, e0, t, sub, cv, hprev, ihcT, hw, out);
        if (has1) do_row(r1, s1, e1, t, sub, cv, hprev, ihcT, hw, out);
        if (t < TSZ - 1) grid_bar(ctl, t);
    }
}

// ---------------- launch ----------------

static inline size_t align256(size_t x) { return (x + 255) & ~(size_t)255; }

extern "C" void kernel_launch(void* const* d_in, const int* in_sizes, int n_in,
                              void* d_out, int out_size, void* d_ws, size_t ws_size,
                              hipStream_t stream) {
    const float* x          = (const float*)d_in[0];
    const float* hh_values  = (const float*)d_in[1];
    const float* hh_bias    = (const float*)d_in[2];
    const float* ih_values  = (const float*)d_in[3];
    const int*   hh_indices = (const int*)d_in[4];
    const int*   ih_indices = (const int*)d_in[5];
    float* out = (float*)d_out;

    char* ws = (char*)d_ws;
    _Float16* X2h   = (_Float16*)ws; ws += align256((size_t)INSZ * 256 * 2);   // 25.6 MB
    half8*  hs      = (half8*)X2h;   // ALIAS: 32 planes x 800KB reuse X2h (R10-proven:
                                     // boundary L2 invalidation at steps_persist launch,
                                     // planes write-once->LLC then read-once).
    half4*  ihcT    = (half4*)ws;  ws += align256((size_t)HSZ * 256 * 2);      // 25.6 MB
    int*    hh_ptr  = (int*)ws;    ws += align256((size_t)(HSZ + 1) * 4);
    int*    ih_ptr  = (int*)ws;    ws += align256((size_t)(HSZ + 1) * 4);
    int*    ghist   = (int*)ws;    ws += align256((size_t)2 * HWORDS * 4);     // 800 KB
    int*    partials= (int*)ws;    ws += align256((size_t)256 * 4);
    int*    cbs     = (int*)ws;    ws += align256((size_t)2 * (NCB + 1) * 4);
    int*    ctl     = (int*)ws;    ws += align256((size_t)1088 * 4);           // barrier tree
    uint2*  tmp_hh  = (uint2*)ws;  ws += align256((size_t)NNZc * 8);           // 6.4 MB
    uint2*  tmp_ih  = (uint2*)ws;  ws += align256((size_t)NNZc * 8);           // 6.4 MB
    unsigned* cv_hh = (unsigned*)ws; ws += align256((size_t)NNZc * 4);         // 3.2 MB
    unsigned* cv_ih = (unsigned*)ws; ws += align256((size_t)NNZc * 4);         // 3.2 MB

    hipMemsetAsync(ctl, 0, (size_t)1088 * 4, stream);   // fresh barrier counters per replay

    p1_count<<<dim3(NBLK, 2), 256, 0, stream>>>(hh_indices, ih_indices, ghist);
    p2scanA<<<dim3(NC2, 2), 1024, 0, stream>>>(ghist, partials);
    p2scanB<<<1, 128, 0, stream>>>(partials);
    p2scanC<<<dim3((HWORDS + 255) / 256, 2), 256, 0, stream>>>(ghist, partials, cbs);
    p2_part<<<dim3(NBLK, 2), 256, 0, stream>>>(hh_indices, hh_values, ih_indices, ih_values,
                                               ghist, tmp_hh, tmp_ih);
    p3_final<<<dim3(NCB, 2), 256, 0, stream>>>(cbs, tmp_hh, tmp_ih,
                                               hh_ptr, ih_ptr, cv_hh, cv_ih);

    transpose_x2<<<(INSZ + 63) / 64, 256, 64 * 257 * 4, stream>>>(x, X2h);
    ihc_kernel<<<HSZ / 4, 256, 0, stream>>>(ih_ptr, cv_ih, hh_bias, (const half4*)X2h, ihcT);

    steps_persist<<<NPB, 256, 0, stream>>>(hh_ptr, cv_hh, (const half8*)ihcT,
                                           hs, out, ctl);
}

// Round 12
// 539.584 us; speedup vs baseline: 1.0971x; 1.0250x over previous
//
#include <hip/hip_runtime.h>
#include <math.h>

#define HSZ 50000
#define INSZ 50000
#define NNZc 800000
#define BSZ 8
#define TSZ 32

#define CHUNK 2048
#define NBLK ((NNZc + CHUNK - 1) / CHUNK)    // 391
#define NCB 196                              // ceil(HSZ/256)
#define HWORDS (256 * NBLK)                  // 100096 per matrix
#define NC2 ((HWORDS + 1023) / 1024)         // 98

// Persistent-normal launch: 784 blocks x 256 thr, 4 waves/block, launch_bounds(256,4)
// -> 4 blocks/CU capacity x 256 CUs = 1024 >= 784: co-resident by capacity (R11-proven).
// 4 lanes/row -> 784*256/4 = 50176 rows in ONE sweep.
#define NPB 784
#define GRPS 8
#define GCNT (NPB / GRPS)                    // 98 arrivals per leaf
#define PFS (NPB / 8)                        // 98 prefetch slices per XCD
#define PFPER ((HSZ * 2 + PFS - 1) / PFS)    // 1021 u64s per slice

typedef _Float16 half8 __attribute__((ext_vector_type(8)));
typedef _Float16 half4 __attribute__((ext_vector_type(4)));

__device__ __forceinline__ unsigned f2h_bits(float f) {
    _Float16 h = (_Float16)f;
    unsigned short u;
    __builtin_memcpy(&u, &h, 2);
    return (unsigned)u;
}
__device__ __forceinline__ float h_bits2f(unsigned u) {
    unsigned short us = (unsigned short)u;
    _Float16 h;
    __builtin_memcpy(&h, &us, 2);
    return (float)h;
}

// ---------------- CSR build: atomic-free radix partition on row>>8 ----------------

__global__ void p1_count(const int* __restrict__ hh_idx, const int* __restrict__ ih_idx,
                         int* __restrict__ ghist) {
    const int* rows = blockIdx.y ? ih_idx : hh_idx;
    __shared__ int cnt[256];
    int tid = threadIdx.x;
    cnt[tid] = 0;
    __syncthreads();
    int base = blockIdx.x * CHUNK;
    int nElem = min(CHUNK, NNZc - base);
    for (int k = tid; k < nElem; k += 256) {
        atomicAdd(&cnt[rows[base + k] >> 8], 1);
    }
    __syncthreads();
    ghist[((size_t)blockIdx.y * 256 + tid) * NBLK + blockIdx.x] = cnt[tid];
}

__global__ void p2scanA(int* __restrict__ ghist, int* __restrict__ partials) {
    int* g = ghist + (size_t)blockIdx.y * HWORDS;
    __shared__ int sm[1024];
    int tid = threadIdx.x;
    int idx = blockIdx.x * 1024 + tid;
    int v = (idx < HWORDS) ? g[idx] : 0;
    sm[tid] = v;
    __syncthreads();
    int x = v;
    for (int off = 1; off < 1024; off <<= 1) {
        int y = (tid >= off) ? sm[tid - off] : 0;
        __syncthreads();
        x += y;
        sm[tid] = x;
        __syncthreads();
    }
    if (idx < HWORDS) g[idx] = x - v;
    if (tid == 1023) partials[blockIdx.y * 128 + blockIdx.x] = x;
}

__global__ void p2scanB(int* __restrict__ partials) {
    __shared__ int sm[128];
    int tid = threadIdx.x;
    for (int m = 0; m < 2; ++m) {
        int v = (tid < NC2) ? partials[m * 128 + tid] : 0;
        sm[tid] = v;
        __syncthreads();
        int x = v;
        for (int off = 1; off < 128; off <<= 1) {
            int y = (tid >= off) ? sm[tid - off] : 0;
            __syncthreads();
            x += y;
            sm[tid] = x;
            __syncthreads();
        }
        if (tid < NC2) partials[m * 128 + tid] = x - v;
        __syncthreads();
    }
}

__global__ void p2scanC(int* __restrict__ ghist, const int* __restrict__ partials,
                        int* __restrict__ cbs) {
    int mat = blockIdx.y;
    int* g = ghist + (size_t)mat * HWORDS;
    int i = blockIdx.x * 256 + threadIdx.x;
    if (i < HWORDS) {
        int v = g[i] + partials[mat * 128 + (i >> 10)];
        g[i] = v;
        int b = i / NBLK;
        if (i - b * NBLK == 0 && b < NCB) cbs[mat * (NCB + 1) + b] = v;
    }
    if (i == 0) cbs[mat * (NCB + 1) + NCB] = NNZc;
}

__global__ void p2_part(const int* __restrict__ hh_idx, const float* __restrict__ hh_v,
                        const int* __restrict__ ih_idx, const float* __restrict__ ih_v,
                        const int* __restrict__ ghist,
                        uint2* __restrict__ tmp_hh, uint2* __restrict__ tmp_ih) {
    int mat = blockIdx.y;
    const int* idx = mat ? ih_idx : hh_idx;
    const float* val = mat ? ih_v : hh_v;
    uint2* tmp = mat ? tmp_ih : tmp_hh;
    const int* g = ghist + (size_t)mat * HWORDS;

    __shared__ int cnt[256];
    __shared__ int lstart[256];
    __shared__ int scanbuf[256];
    __shared__ int gbase[256];
    __shared__ uint2 stage[CHUNK];

    int tid = threadIdx.x;
    int base = blockIdx.x * CHUNK;
    int nElem = min(CHUNK, NNZc - base);

    cnt[tid] = 0;
    gbase[tid] = g[(size_t)tid * NBLK + blockIdx.x];
    __syncthreads();
    for (int k = tid; k < nElem; k += 256) {
        atomicAdd(&cnt[idx[base + k] >> 8], 1);
    }
    __syncthreads();
    int v = cnt[tid];
    scanbuf[tid] = v;
    __syncthreads();
    int x = v;
    for (int off = 1; off < 256; off <<= 1) {
        int y = (tid >= off) ? scanbuf[tid - off] : 0;
        __syncthreads();
        x += y;
        scanbuf[tid] = x;
        __syncthreads();
    }
    lstart[tid] = x - v;
    cnt[tid] = 0;
    __syncthreads();
    for (int k = tid; k < nElem; k += 256) {
        int r = idx[base + k];
        int c = idx[NNZc + base + k];
        int b = r >> 8;
        int rank = atomicAdd(&cnt[b], 1);
        stage[lstart[b] + rank] = make_uint2(((unsigned)r << 16) | (unsigned)c,
                                             __float_as_uint(val[base + k]));
    }
    __syncthreads();
    for (int k = tid; k < nElem; k += 256) {
        uint2 el = stage[k];
        int b = el.x >> 24;
        tmp[gbase[b] + (k - lstart[b])] = el;
    }
}

__global__ void p3_final(const int* __restrict__ cbs,
                         const uint2* __restrict__ tmp_hh, const uint2* __restrict__ tmp_ih,
                         int* __restrict__ ptr_hh, int* __restrict__ ptr_ih,
                         unsigned* __restrict__ cv_hh, unsigned* __restrict__ cv_ih) {
    int mat = blockIdx.y;
    const uint2* tmp = mat ? tmp_ih : tmp_hh;
    int* ptr = mat ? ptr_ih : ptr_hh;
    unsigned* cv = mat ? cv_ih : cv_hh;
    __shared__ int rcnt[256];
    __shared__ int rstart[256];
    __shared__ int scanbuf[256];
    int cb = blockIdx.x;
    int row0 = cb << 8;
    int nrows = min(256, HSZ - row0);
    int s = cbs[mat * (NCB + 1) + cb];
    int e = cbs[mat * (NCB + 1) + cb + 1];
    int tid = threadIdx.x;
    rcnt[tid] = 0;
    __syncthreads();
    for (int k = s + tid; k < e; k += 256) {
        atomicAdd(&rcnt[(tmp[k].x >> 16) & 255], 1);
    }
    __syncthreads();
    int v = rcnt[tid];
    scanbuf[tid] = v;
    __syncthreads();
    int x = v;
    for (int off = 1; off < 256; off <<= 1) {
        int y = (tid >= off) ? scanbuf[tid - off] : 0;
        __syncthreads();
        x += y;
        scanbuf[tid] = x;
        __syncthreads();
    }
    rstart[tid] = x - v;
    if (tid < nrows) ptr[row0 + tid] = s + x - v;
    if (cb == NCB - 1 && tid == 0) ptr[HSZ] = NNZc;
    rcnt[tid] = 0;
    __syncthreads();
    for (int k = s + tid; k < e; k += 256) {
        uint2 el = tmp[k];
        int lr = (el.x >> 16) & 255;
        int rank = atomicAdd(&rcnt[lr], 1);
        cv[s + rstart[lr] + rank] =
            (f2h_bits(__uint_as_float(el.y)) << 16) | (el.x & 0xffffu);
    }
}

// ---------------- transpose: x (B,T,IN) -> X2h (IN, 256) fp16, col = t*8+b ----------------

__global__ void transpose_x2(const float* __restrict__ x, _Float16* __restrict__ X2h) {
    extern __shared__ float tile[];   // 64 * 257 floats
    int i0 = blockIdx.x * 64;
    int tid = threadIdx.x;
    int il = tid & 15;
    int tr = (tid >> 4) & 3;
    int tg = tid >> 6;
#pragma unroll
    for (int iter = 0; iter < 16; ++iter) {
        int tb = iter * 16 + tg * 4 + tr;
        int t = tb >> 3, b = tb & 7;
        const float4 v = *reinterpret_cast<const float4*>(
            x + ((size_t)b * TSZ + t) * INSZ + i0 + il * 4);
        tile[(il * 4 + 0) * 257 + tb] = v.x;
        tile[(il * 4 + 1) * 257 + tb] = v.y;
        tile[(il * 4 + 2) * 257 + tb] = v.z;
        tile[(il * 4 + 3) * 257 + tb] = v.w;
    }
    __syncthreads();
    for (int k = 0; k < 64; ++k) {
        int i = i0 + k;
        if (i < INSZ) X2h[(size_t)i * 256 + tid] = (_Float16)tile[k * 257 + tid];
    }
}

// ---------------- ihc v5: one wave per row, 4-deep gather pipeline (fabric-BW floor) ----------------

__global__ void ihc_kernel(const int* __restrict__ ptr, const unsigned* __restrict__ cv,
                           const float* __restrict__ bias, const half4* __restrict__ X2h,
                           half4* __restrict__ ihcT) {
    __shared__ half4 lds[4 * 65];
    int wid = threadIdx.x >> 6;
    int lane = threadIdx.x & 63;
    int r = (blockIdx.x << 2) + wid;
    int s = ptr[r], e = ptr[r + 1];
    s = __builtin_amdgcn_readfirstlane(s);
    e = __builtin_amdgcn_readfirstlane(e);
    float4 acc = make_float4(0.f, 0.f, 0.f, 0.f);
    int j = s;
    for (; j + 3 < e; j += 4) {
        unsigned a = cv[j], b = cv[j + 1], c = cv[j + 2], d = cv[j + 3];
        float va = h_bits2f(a >> 16);
        float vb = h_bits2f(b >> 16);
        float vc = h_bits2f(c >> 16);
        float vd = h_bits2f(d >> 16);
        half4 x0 = X2h[((size_t)(a & 0xffffu) << 6) + lane];
        half4 x1 = X2h[((size_t)(b & 0xffffu) << 6) + lane];
        half4 x2 = X2h[((size_t)(c & 0xffffu) << 6) + lane];
        half4 x3 = X2h[((size_t)(d & 0xffffu) << 6) + lane];
        acc.x = fmaf(va, (float)x0[0], acc.x);
        acc.y = fmaf(va, (float)x0[1], acc.y);
        acc.z = fmaf(va, (float)x0[2], acc.z);
        acc.w = fmaf(va, (float)x0[3], acc.w);
        acc.x = fmaf(vb, (float)x1[0], acc.x);
        acc.y = fmaf(vb, (float)x1[1], acc.y);
        acc.z = fmaf(vb, (float)x1[2], acc.z);
        acc.w = fmaf(vb, (float)x1[3], acc.w);
        acc.x = fmaf(vc, (float)x2[0], acc.x);
        acc.y = fmaf(vc, (float)x2[1], acc.y);
        acc.z = fmaf(vc, (float)x2[2], acc.z);
        acc.w = fmaf(vc, (float)x2[3], acc.w);
        acc.x = fmaf(vd, (float)x3[0], acc.x);
        acc.y = fmaf(vd, (float)x3[1], acc.y);
        acc.z = fmaf(vd, (float)x3[2], acc.z);
        acc.w = fmaf(vd, (float)x3[3], acc.w);
    }
    for (; j < e; ++j) {
        unsigned a = cv[j];
        float va = h_bits2f(a >> 16);
        half4 x0 = X2h[((size_t)(a & 0xffffu) << 6) + lane];
        acc.x = fmaf(va, (float)x0[0], acc.x);
        acc.y = fmaf(va, (float)x0[1], acc.y);
        acc.z = fmaf(va, (float)x0[2], acc.z);
        acc.w = fmaf(va, (float)x0[3], acc.w);
    }
    float bb = bias[r];
    half4 o;
    o[0] = (_Float16)(acc.x + bb);
    o[1] = (_Float16)(acc.y + bb);
    o[2] = (_Float16)(acc.z + bb);
    o[3] = (_Float16)(acc.w + bb);
    lds[wid * 65 + lane] = o;
    __syncthreads();
    int plane = threadIdx.x >> 3;
    int w = threadIdx.x & 7;
    int row = w >> 1, q = w & 1;
    int r2 = (blockIdx.x << 2) + row;
    ihcT[((size_t)plane * HSZ + r2) * 2 + q] = lds[row * 65 + 2 * plane + q];
}

// ---------------- persistent recurrence v5: single sweep, 4 lanes/row, L2 prefetch ----------------
// R10/R11 proved: cached gathers + write-through h + tree barrier are CORRECT; per-step
// cost ~11us dominated by gather latency (h[t-1] lines first-touch-miss each XCD's L2).
// v5: (a) each block streams a contiguous slice of h[t-1] (coalesced, kept alive via
// empty asm) so the plane enters this XCD's L2 as a sequential sweep racing the gathers;
// (b) 4 lanes/row single sweep: R7/R9's exact reduction order, 2 shuffle stages, no 2nd row.

__device__ __forceinline__ float fast_tanh(float x) {
    float e = __expf(2.0f * x);
    return 1.0f - __fdividef(2.0f, e + 1.0f);
}

// ctl layout (ints): leaf[g*64 + t], root[512 + t], rel[576 + g*64]
__device__ __forceinline__ void grid_bar(int* __restrict__ ctl, int t) {
    __syncthreads();   // drains vmcnt(0): this block's h write-through stores are at LLC
    if (threadIdx.x == 0) {
        int g = blockIdx.x & 7;
        __hip_atomic_fetch_add(&ctl[g * 64 + t], 1, __ATOMIC_RELAXED,
                               __HIP_MEMORY_SCOPE_AGENT);   // fire-and-forget arrival
        if (blockIdx.x < 8) {   // leader of group g == blockIdx.x
            while (__hip_atomic_load(&ctl[g * 64 + t], __ATOMIC_RELAXED,
                                     __HIP_MEMORY_SCOPE_AGENT) < GCNT)
                __builtin_amdgcn_s_sleep(1);
            __hip_atomic_fetch_add(&ctl[512 + t], 1, __ATOMIC_RELAXED,
                                   __HIP_MEMORY_SCOPE_AGENT);
            while (__hip_atomic_load(&ctl[512 + t], __ATOMIC_RELAXED,
                                     __HIP_MEMORY_SCOPE_AGENT) < GRPS)
                __builtin_amdgcn_s_sleep(1);
            __hip_atomic_store(&ctl[576 + g * 64], t + 1, __ATOMIC_RELAXED,
                               __HIP_MEMORY_SCOPE_AGENT);
        } else {
            while (__hip_atomic_load(&ctl[576 + g * 64], __ATOMIC_RELAXED,
                                     __HIP_MEMORY_SCOPE_AGENT) <= t)
                __builtin_amdgcn_s_sleep(8);
        }
    }
    __syncthreads();
}

__global__ void __launch_bounds__(256, 4) steps_persist(
        const int* __restrict__ ptr, const unsigned* __restrict__ cv,
        const half8* __restrict__ ihcT, half8* __restrict__ hs,
        float* __restrict__ out, int* __restrict__ ctl) {
    int tid = threadIdx.x;
    int sub = tid & 3;
    int r = blockIdx.x * 64 + (tid >> 2);            // < 50176
    bool active = (r < HSZ);
    int s = 0, e = 0;
    if (active) { s = ptr[r]; e = ptr[r + 1]; }
    int j0 = s + (sub << 1);
    // prefetch slice bounds (same every step; plane base changes)
    int pbase = (blockIdx.x >> 3) * PFPER + tid;
    int pend = min((blockIdx.x >> 3) * PFPER + PFPER, HSZ * 2);

    for (int t = 0; t < TSZ; ++t) {
        const half8* __restrict__ hprev = hs + (size_t)(t > 0 ? t - 1 : 0) * HSZ;
        unsigned long long* __restrict__ hw =
            (unsigned long long*)(hs + (size_t)t * HSZ);

        float a0 = 0.f, a1 = 0.f, a2 = 0.f, a3 = 0.f;
        float a4 = 0.f, a5 = 0.f, a6 = 0.f, a7 = 0.f;
        if (t > 0) {
            // ---- issue streaming prefetch of this XCD's slice of h[t-1] (no wait) ----
            const unsigned long long* hp = (const unsigned long long*)hprev;
            unsigned long long q0 = 0, q1 = 0, q2 = 0, q3 = 0;
            if (pbase < pend)       q0 = hp[pbase];
            if (pbase + 256 < pend) q1 = hp[pbase + 256];
            if (pbase + 512 < pend) q2 = hp[pbase + 512];
            if (pbase + 768 < pend) q3 = hp[pbase + 768];
            // ---- gathers (race the prefetch; L2 MSHR coalesces duplicate lines) ----
            if (active) {
                int j = j0;
                for (; j + 1 < e; j += 8) {
                    unsigned u0 = cv[j];
                    unsigned u1 = cv[j + 1];
                    float v0 = h_bits2f(u0 >> 16);
                    float v1 = h_bits2f(u1 >> 16);
                    half8 hv0 = hprev[u0 & 0xffffu];
                    half8 hv1 = hprev[u1 & 0xffffu];
                    a0 = fmaf(v0, (float)hv0[0], a0);
                    a1 = fmaf(v0, (float)hv0[1], a1);
                    a2 = fmaf(v0, (float)hv0[2], a2);
                    a3 = fmaf(v0, (float)hv0[3], a3);
                    a4 = fmaf(v0, (float)hv0[4], a4);
                    a5 = fmaf(v0, (float)hv0[5], a5);
                    a6 = fmaf(v0, (float)hv0[6], a6);
                    a7 = fmaf(v0, (float)hv0[7], a7);
                    a0 = fmaf(v1, (float)hv1[0], a0);
                    a1 = fmaf(v1, (float)hv1[1], a1);
                    a2 = fmaf(v1, (float)hv1[2], a2);
                    a3 = fmaf(v1, (float)hv1[3], a3);
                    a4 = fmaf(v1, (float)hv1[4], a4);
                    a5 = fmaf(v1, (float)hv1[5], a5);
                    a6 = fmaf(v1, (float)hv1[6], a6);
                    a7 = fmaf(v1, (float)hv1[7], a7);
                }
                if (j < e) {
                    unsigned u0 = cv[j];
                    float v0 = h_bits2f(u0 >> 16);
                    half8 hv0 = hprev[u0 & 0xffffu];
                    a0 = fmaf(v0, (float)hv0[0], a0);
                    a1 = fmaf(v0, (float)hv0[1], a1);
                    a2 = fmaf(v0, (float)hv0[2], a2);
                    a3 = fmaf(v0, (float)hv0[3], a3);
                    a4 = fmaf(v0, (float)hv0[4], a4);
                    a5 = fmaf(v0, (float)hv0[5], a5);
                    a6 = fmaf(v0, (float)hv0[6], a6);
                    a7 = fmaf(v0, (float)hv0[7], a7);
                }
            }
            // keep prefetch results live (forces the loads to retire, lines now in L2)
            asm volatile("" :: "v"(q0), "v"(q1), "v"(q2), "v"(q3));
        }
        a0 += __shfl_xor(a0, 1); a1 += __shfl_xor(a1, 1);
        a2 += __shfl_xor(a2, 1); a3 += __shfl_xor(a3, 1);
        a4 += __shfl_xor(a4, 1); a5 += __shfl_xor(a5, 1);
        a6 += __shfl_xor(a6, 1); a7 += __shfl_xor(a7, 1);
        a0 += __shfl_xor(a0, 2); a1 += __shfl_xor(a1, 2);
        a2 += __shfl_xor(a2, 2); a3 += __shfl_xor(a3, 2);
        a4 += __shfl_xor(a4, 2); a5 += __shfl_xor(a5, 2);
        a6 += __shfl_xor(a6, 2); a7 += __shfl_xor(a7, 2);

        if (active && sub == 0) {
            half8 b8 = ihcT[(size_t)t * HSZ + r];
            float h0 = fast_tanh(a0 + (float)b8[0]);
            float h1 = fast_tanh(a1 + (float)b8[1]);
            float h2 = fast_tanh(a2 + (float)b8[2]);
            float h3 = fast_tanh(a3 + (float)b8[3]);
            float h4 = fast_tanh(a4 + (float)b8[4]);
            float h5 = fast_tanh(a5 + (float)b8[5]);
            float h6 = fast_tanh(a6 + (float)b8[6]);
            float h7 = fast_tanh(a7 + (float)b8[7]);
            half8 hh;
            hh[0] = (_Float16)h0; hh[1] = (_Float16)h1;
            hh[2] = (_Float16)h2; hh[3] = (_Float16)h3;
            hh[4] = (_Float16)h4; hh[5] = (_Float16)h5;
            hh[6] = (_Float16)h6; hh[7] = (_Float16)h7;
            union { half8 h; unsigned long long q[2]; } u2;
            u2.h = hh;
            __hip_atomic_store(hw + ((size_t)r << 1), u2.q[0], __ATOMIC_RELAXED,
                               __HIP_MEMORY_SCOPE_AGENT);       // write-through -> LLC
            __hip_atomic_store(hw + ((size_t)r << 1) + 1, u2.q[1], __ATOMIC_RELAXED,
                               __HIP_MEMORY_SCOPE_AGENT);
            __builtin_nontemporal_store(h0, &out[((size_t)0 * TSZ + t) * HSZ + r]);
            __builtin_nontemporal_store(h1, &out[((size_t)1 * TSZ + t) * HSZ + r]);
            __builtin_nontemporal_store(h2, &out[((size_t)2 * TSZ + t) * HSZ + r]);
            __builtin_nontemporal_store(h3, &out[((size_t)3 * TSZ + t) * HSZ + r]);
            __builtin_nontemporal_store(h4, &out[((size_t)4 * TSZ + t) * HSZ + r]);
            __builtin_nontemporal_store(h5, &out[((size_t)5 * TSZ + t) * HSZ + r]);
            __builtin_nontemporal_store(h6, &out[((size_t)6 * TSZ + t) * HSZ + r]);
            __builtin_nontemporal_store(h7, &out[((size_t)7 * TSZ + t) * HSZ + r]);
        }
        if (t < TSZ - 1) grid_bar(ctl, t);
    }
}

// ---------------- launch ----------------

static inline size_t align256(size_t x) { return (x + 255) & ~(size_t)255; }

extern "C" void kernel_launch(void* const* d_in, const int* in_sizes, int n_in,
                              void* d_out, int out_size, void* d_ws, size_t ws_size,
                              hipStream_t stream) {
    const float* x          = (const float*)d_in[0];
    const float* hh_values  = (const float*)d_in[1];
    const float* hh_bias    = (const float*)d_in[2];
    const float* ih_values  = (const float*)d_in[3];
    const int*   hh_indices = (const int*)d_in[4];
    const int*   ih_indices = (const int*)d_in[5];
    float* out = (float*)d_out;

    char* ws = (char*)d_ws;
    _Float16* X2h   = (_Float16*)ws; ws += align256((size_t)INSZ * 256 * 2);   // 25.6 MB
    half8*  hs      = (half8*)X2h;   // ALIAS: 32 planes x 800KB reuse X2h (R10-proven).
    half4*  ihcT    = (half4*)ws;  ws += align256((size_t)HSZ * 256 * 2);      // 25.6 MB
    int*    hh_ptr  = (int*)ws;    ws += align256((size_t)(HSZ + 1) * 4);
    int*    ih_ptr  = (int*)ws;    ws += align256((size_t)(HSZ + 1) * 4);
    int*    ghist   = (int*)ws;    ws += align256((size_t)2 * HWORDS * 4);     // 800 KB
    int*    partials= (int*)ws;    ws += align256((size_t)256 * 4);
    int*    cbs     = (int*)ws;    ws += align256((size_t)2 * (NCB + 1) * 4);
    int*    ctl     = (int*)ws;    ws += align256((size_t)1088 * 4);           // barrier tree
    uint2*  tmp_hh  = (uint2*)ws;  ws += align256((size_t)NNZc * 8);           // 6.4 MB
    uint2*  tmp_ih  = (uint2*)ws;  ws += align256((size_t)NNZc * 8);           // 6.4 MB
    unsigned* cv_hh = (unsigned*)ws; ws += align256((size_t)NNZc * 4);         // 3.2 MB
    unsigned* cv_ih = (unsigned*)ws; ws += align256((size_t)NNZc * 4);         // 3.2 MB

    hipMemsetAsync(ctl, 0, (size_t)1088 * 4, stream);   // fresh barrier counters per replay

    p1_count<<<dim3(NBLK, 2), 256, 0, stream>>>(hh_indices, ih_indices, ghist);
    p2scanA<<<dim3(NC2, 2), 1024, 0, stream>>>(ghist, partials);
    p2scanB<<<1, 128, 0, stream>>>(partials);
    p2scanC<<<dim3((HWORDS + 255) / 256, 2), 256, 0, stream>>>(ghist, partials, cbs);
    p2_part<<<dim3(NBLK, 2), 256, 0, stream>>>(hh_indices, hh_values, ih_indices, ih_values,
                                               ghist, tmp_hh, tmp_ih);
    p3_final<<<dim3(NCB, 2), 256, 0, stream>>>(cbs, tmp_hh, tmp_ih,
                                               hh_ptr, ih_ptr, cv_hh, cv_ih);

    transpose_x2<<<(INSZ + 63) / 64, 256, 64 * 257 * 4, stream>>>(x, X2h);
    ihc_kernel<<<HSZ / 4, 256, 0, stream>>>(ih_ptr, cv_ih, hh_bias, (const half4*)X2h, ihcT);

    steps_persist<<<NPB, 256, 0, stream>>>(hh_ptr, cv_hh, (const half8*)ihcT,
                                           hs, out, ctl);
}

// Round 14
// 495.622 us; speedup vs baseline: 1.1944x; 1.0887x over previous
//
#include <hip/hip_runtime.h>
#include <math.h>

#define HSZ 50000
#define INSZ 50000
#define NNZc 800000
#define BSZ 8
#define TSZ 32

#define CHUNK 2048
#define NBLK ((NNZc + CHUNK - 1) / CHUNK)    // 391
#define NCB 196                              // ceil(HSZ/256)
#define HWORDS (256 * NBLK)                  // 100096 per matrix
#define NC2 ((HWORDS + 1023) / 1024)         // 98

typedef _Float16 half8 __attribute__((ext_vector_type(8)));
typedef _Float16 half4 __attribute__((ext_vector_type(4)));

__device__ __forceinline__ unsigned f2h_bits(float f) {
    _Float16 h = (_Float16)f;
    unsigned short u;
    __builtin_memcpy(&u, &h, 2);
    return (unsigned)u;
}
__device__ __forceinline__ float h_bits2f(unsigned u) {
    unsigned short us = (unsigned short)u;
    _Float16 h;
    __builtin_memcpy(&h, &us, 2);
    return (float)h;
}

// ---------------- CSR build: atomic-free radix partition on row>>8 ----------------

__global__ void p1_count(const int* __restrict__ hh_idx, const int* __restrict__ ih_idx,
                         int* __restrict__ ghist) {
    const int* rows = blockIdx.y ? ih_idx : hh_idx;
    __shared__ int cnt[256];
    int tid = threadIdx.x;
    cnt[tid] = 0;
    __syncthreads();
    int base = blockIdx.x * CHUNK;
    int nElem = min(CHUNK, NNZc - base);
    for (int k = tid; k < nElem; k += 256) {
        atomicAdd(&cnt[rows[base + k] >> 8], 1);
    }
    __syncthreads();
    ghist[((size_t)blockIdx.y * 256 + tid) * NBLK + blockIdx.x] = cnt[tid];
}

__global__ void p2scanA(int* __restrict__ ghist, int* __restrict__ partials) {
    int* g = ghist + (size_t)blockIdx.y * HWORDS;
    __shared__ int sm[1024];
    int tid = threadIdx.x;
    int idx = blockIdx.x * 1024 + tid;
    int v = (idx < HWORDS) ? g[idx] : 0;
    sm[tid] = v;
    __syncthreads();
    int x = v;
    for (int off = 1; off < 1024; off <<= 1) {
        int y = (tid >= off) ? sm[tid - off] : 0;
        __syncthreads();
        x += y;
        sm[tid] = x;
        __syncthreads();
    }
    if (idx < HWORDS) g[idx] = x - v;
    if (tid == 1023) partials[blockIdx.y * 128 + blockIdx.x] = x;
}

__global__ void p2scanB(int* __restrict__ partials) {
    __shared__ int sm[128];
    int tid = threadIdx.x;
    for (int m = 0; m < 2; ++m) {
        int v = (tid < NC2) ? partials[m * 128 + tid] : 0;
        sm[tid] = v;
        __syncthreads();
        int x = v;
        for (int off = 1; off < 128; off <<= 1) {
            int y = (tid >= off) ? sm[tid - off] : 0;
            __syncthreads();
            x += y;
            sm[tid] = x;
            __syncthreads();
        }
        if (tid < NC2) partials[m * 128 + tid] = x - v;
        __syncthreads();
    }
}

__global__ void p2scanC(int* __restrict__ ghist, const int* __restrict__ partials,
                        int* __restrict__ cbs) {
    int mat = blockIdx.y;
    int* g = ghist + (size_t)mat * HWORDS;
    int i = blockIdx.x * 256 + threadIdx.x;
    if (i < HWORDS) {
        int v = g[i] + partials[mat * 128 + (i >> 10)];
        g[i] = v;
        int b = i / NBLK;
        if (i - b * NBLK == 0 && b < NCB) cbs[mat * (NCB + 1) + b] = v;
    }
    if (i == 0) cbs[mat * (NCB + 1) + NCB] = NNZc;
}

__global__ void p2_part(const int* __restrict__ hh_idx, const float* __restrict__ hh_v,
                        const int* __restrict__ ih_idx, const float* __restrict__ ih_v,
                        const int* __restrict__ ghist,
                        uint2* __restrict__ tmp_hh, uint2* __restrict__ tmp_ih) {
    int mat = blockIdx.y;
    const int* idx = mat ? ih_idx : hh_idx;
    const float* val = mat ? ih_v : hh_v;
    uint2* tmp = mat ? tmp_ih : tmp_hh;
    const int* g = ghist + (size_t)mat * HWORDS;

    __shared__ int cnt[256];
    __shared__ int lstart[256];
    __shared__ int scanbuf[256];
    __shared__ int gbase[256];
    __shared__ uint2 stage[CHUNK];

    int tid = threadIdx.x;
    int base = blockIdx.x * CHUNK;
    int nElem = min(CHUNK, NNZc - base);

    cnt[tid] = 0;
    gbase[tid] = g[(size_t)tid * NBLK + blockIdx.x];
    __syncthreads();
    for (int k = tid; k < nElem; k += 256) {
        atomicAdd(&cnt[idx[base + k] >> 8], 1);
    }
    __syncthreads();
    int v = cnt[tid];
    scanbuf[tid] = v;
    __syncthreads();
    int x = v;
    for (int off = 1; off < 256; off <<= 1) {
        int y = (tid >= off) ? scanbuf[tid - off] : 0;
        __syncthreads();
        x += y;
        scanbuf[tid] = x;
        __syncthreads();
    }
    lstart[tid] = x - v;
    cnt[tid] = 0;
    __syncthreads();
    for (int k = tid; k < nElem; k += 256) {
        int r = idx[base + k];
        int c = idx[NNZc + base + k];
        int b = r >> 8;
        int rank = atomicAdd(&cnt[b], 1);
        stage[lstart[b] + rank] = make_uint2(((unsigned)r << 16) | (unsigned)c,
                                             __float_as_uint(val[base + k]));
    }
    __syncthreads();
    for (int k = tid; k < nElem; k += 256) {
        uint2 el = stage[k];
        int b = el.x >> 24;
        tmp[gbase[b] + (k - lstart[b])] = el;
    }
}

__global__ void p3_final(const int* __restrict__ cbs,
                         const uint2* __restrict__ tmp_hh, const uint2* __restrict__ tmp_ih,
                         int* __restrict__ ptr_hh, int* __restrict__ ptr_ih,
                         unsigned* __restrict__ cv_hh, unsigned* __restrict__ cv_ih) {
    int mat = blockIdx.y;
    const uint2* tmp = mat ? tmp_ih : tmp_hh;
    int* ptr = mat ? ptr_ih : ptr_hh;
    unsigned* cv = mat ? cv_ih : cv_hh;
    __shared__ int rcnt[256];
    __shared__ int rstart[256];
    __shared__ int scanbuf[256];
    int cb = blockIdx.x;
    int row0 = cb << 8;
    int nrows = min(256, HSZ - row0);
    int s = cbs[mat * (NCB + 1) + cb];
    int e = cbs[mat * (NCB + 1) + cb + 1];
    int tid = threadIdx.x;
    rcnt[tid] = 0;
    __syncthreads();
    for (int k = s + tid; k < e; k += 256) {
        atomicAdd(&rcnt[(tmp[k].x >> 16) & 255], 1);
    }
    __syncthreads();
    int v = rcnt[tid];
    scanbuf[tid] = v;
    __syncthreads();
    int x = v;
    for (int off = 1; off < 256; off <<= 1) {
        int y = (tid >= off) ? scanbuf[tid - off] : 0;
        __syncthreads();
        x += y;
        scanbuf[tid] = x;
        __syncthreads();
    }
    rstart[tid] = x - v;
    if (tid < nrows) ptr[row0 + tid] = s + x - v;
    if (cb == NCB - 1 && tid == 0) ptr[HSZ] = NNZc;
    rcnt[tid] = 0;
    __syncthreads();
    for (int k = s + tid; k < e; k += 256) {
        uint2 el = tmp[k];
        int lr = (el.x >> 16) & 255;
        int rank = atomicAdd(&rcnt[lr], 1);
        cv[s + rstart[lr] + rank] =
            (f2h_bits(__uint_as_float(el.y)) << 16) | (el.x & 0xffffu);
    }
}

// ---------------- transpose: x (B,T,IN) -> X2h (IN, 256) fp16, col = t*8+b ----------------

__global__ void transpose_x2(const float* __restrict__ x, _Float16* __restrict__ X2h) {
    extern __shared__ float tile[];   // 64 * 257 floats
    int i0 = blockIdx.x * 64;
    int tid = threadIdx.x;
    int il = tid & 15;
    int tr = (tid >> 4) & 3;
    int tg = tid >> 6;
#pragma unroll
    for (int iter = 0; iter < 16; ++iter) {
        int tb = iter * 16 + tg * 4 + tr;
        int t = tb >> 3, b = tb & 7;
        const float4 v = *reinterpret_cast<const float4*>(
            x + ((size_t)b * TSZ + t) * INSZ + i0 + il * 4);
        tile[(il * 4 + 0) * 257 + tb] = v.x;
        tile[(il * 4 + 1) * 257 + tb] = v.y;
        tile[(il * 4 + 2) * 257 + tb] = v.z;
        tile[(il * 4 + 3) * 257 + tb] = v.w;
    }
    __syncthreads();
    for (int k = 0; k < 64; ++k) {
        int i = i0 + k;
        if (i < INSZ) X2h[(size_t)i * 256 + tid] = (_Float16)tile[k * 257 + tid];
    }
}

// ---------------- ihc v5: one wave per row, 4-deep gather pipeline (fabric-BW floor) ----------------

__global__ void ihc_kernel(const int* __restrict__ ptr, const unsigned* __restrict__ cv,
                           const float* __restrict__ bias, const half4* __restrict__ X2h,
                           half4* __restrict__ ihcT) {
    __shared__ half4 lds[4 * 65];
    int wid = threadIdx.x >> 6;
    int lane = threadIdx.x & 63;
    int r = (blockIdx.x << 2) + wid;
    int s = ptr[r], e = ptr[r + 1];
    s = __builtin_amdgcn_readfirstlane(s);
    e = __builtin_amdgcn_readfirstlane(e);
    float4 acc = make_float4(0.f, 0.f, 0.f, 0.f);
    int j = s;
    for (; j + 3 < e; j += 4) {
        unsigned a = cv[j], b = cv[j + 1], c = cv[j + 2], d = cv[j + 3];
        float va = h_bits2f(a >> 16);
        float vb = h_bits2f(b >> 16);
        float vc = h_bits2f(c >> 16);
        float vd = h_bits2f(d >> 16);
        half4 x0 = X2h[((size_t)(a & 0xffffu) << 6) + lane];
        half4 x1 = X2h[((size_t)(b & 0xffffu) << 6) + lane];
        half4 x2 = X2h[((size_t)(c & 0xffffu) << 6) + lane];
        half4 x3 = X2h[((size_t)(d & 0xffffu) << 6) + lane];
        acc.x = fmaf(va, (float)x0[0], acc.x);
        acc.y = fmaf(va, (float)x0[1], acc.y);
        acc.z = fmaf(va, (float)x0[2], acc.z);
        acc.w = fmaf(va, (float)x0[3], acc.w);
        acc.x = fmaf(vb, (float)x1[0], acc.x);
        acc.y = fmaf(vb, (float)x1[1], acc.y);
        acc.z = fmaf(vb, (float)x1[2], acc.z);
        acc.w = fmaf(vb, (float)x1[3], acc.w);
        acc.x = fmaf(vc, (float)x2[0], acc.x);
        acc.y = fmaf(vc, (float)x2[1], acc.y);
        acc.z = fmaf(vc, (float)x2[2], acc.z);
        acc.w = fmaf(vc, (float)x2[3], acc.w);
        acc.x = fmaf(vd, (float)x3[0], acc.x);
        acc.y = fmaf(vd, (float)x3[1], acc.y);
        acc.z = fmaf(vd, (float)x3[2], acc.z);
        acc.w = fmaf(vd, (float)x3[3], acc.w);
    }
    for (; j < e; ++j) {
        unsigned a = cv[j];
        float va = h_bits2f(a >> 16);
        half4 x0 = X2h[((size_t)(a & 0xffffu) << 6) + lane];
        acc.x = fmaf(va, (float)x0[0], acc.x);
        acc.y = fmaf(va, (float)x0[1], acc.y);
        acc.z = fmaf(va, (float)x0[2], acc.z);
        acc.w = fmaf(va, (float)x0[3], acc.w);
    }
    float bb = bias[r];
    half4 o;
    o[0] = (_Float16)(acc.x + bb);
    o[1] = (_Float16)(acc.y + bb);
    o[2] = (_Float16)(acc.z + bb);
    o[3] = (_Float16)(acc.w + bb);
    lds[wid * 65 + lane] = o;
    __syncthreads();
    int plane = threadIdx.x >> 3;
    int w = threadIdx.x & 7;
    int row = w >> 1, q = w & 1;
    int r2 = (blockIdx.x << 2) + row;
    ihcT[((size_t)plane * HSZ + r2) * 2 + q] = lds[row * 65 + 2 * plane + q];
}

// ---------------- recurrence step v6 (best measured): 4 lanes/row, paired cached gathers ----------------

__device__ __forceinline__ float fast_tanh(float x) {
    float e = __expf(2.0f * x);
    return 1.0f - __fdividef(2.0f, e + 1.0f);
}

__global__ void step_kernel(const int* __restrict__ ptr, const unsigned* __restrict__ cv,
                            const half8* __restrict__ ihcT, const half8* __restrict__ h_in,
                            half8* __restrict__ h_out, float* __restrict__ out, int t) {
    int gid = blockIdx.x * 256 + threadIdx.x;    // gid = r*4 + sub
    if (gid >= 4 * HSZ) return;
    int sub = gid & 3;
    int r = gid >> 2;
    int s = ptr[r], e = ptr[r + 1];
    half8 base8;
    bool lead = (sub == 0);
    if (lead) base8 = ihcT[(size_t)t * HSZ + r];
    float a0 = 0.f, a1 = 0.f, a2 = 0.f, a3 = 0.f;
    float a4 = 0.f, a5 = 0.f, a6 = 0.f, a7 = 0.f;
    if (t > 0) {
        int j = s + (sub << 1);
        for (; j + 1 < e; j += 8) {
            unsigned u0 = cv[j];
            unsigned u1 = cv[j + 1];
            float v0 = h_bits2f(u0 >> 16);
            float v1 = h_bits2f(u1 >> 16);
            half8 hv0 = h_in[u0 & 0xffffu];
            half8 hv1 = h_in[u1 & 0xffffu];
            a0 = fmaf(v0, (float)hv0[0], a0);
            a1 = fmaf(v0, (float)hv0[1], a1);
            a2 = fmaf(v0, (float)hv0[2], a2);
            a3 = fmaf(v0, (float)hv0[3], a3);
            a4 = fmaf(v0, (float)hv0[4], a4);
            a5 = fmaf(v0, (float)hv0[5], a5);
            a6 = fmaf(v0, (float)hv0[6], a6);
            a7 = fmaf(v0, (float)hv0[7], a7);
            a0 = fmaf(v1, (float)hv1[0], a0);
            a1 = fmaf(v1, (float)hv1[1], a1);
            a2 = fmaf(v1, (float)hv1[2], a2);
            a3 = fmaf(v1, (float)hv1[3], a3);
            a4 = fmaf(v1, (float)hv1[4], a4);
            a5 = fmaf(v1, (float)hv1[5], a5);
            a6 = fmaf(v1, (float)hv1[6], a6);
            a7 = fmaf(v1, (float)hv1[7], a7);
        }
        if (j < e) {
            unsigned u0 = cv[j];
            float v0 = h_bits2f(u0 >> 16);
            half8 hv0 = h_in[u0 & 0xffffu];
            a0 = fmaf(v0, (float)hv0[0], a0);
            a1 = fmaf(v0, (float)hv0[1], a1);
            a2 = fmaf(v0, (float)hv0[2], a2);
            a3 = fmaf(v0, (float)hv0[3], a3);
            a4 = fmaf(v0, (float)hv0[4], a4);
            a5 = fmaf(v0, (float)hv0[5], a5);
            a6 = fmaf(v0, (float)hv0[6], a6);
            a7 = fmaf(v0, (float)hv0[7], a7);
        }
    }
    a0 += __shfl_xor(a0, 1); a1 += __shfl_xor(a1, 1);
    a2 += __shfl_xor(a2, 1); a3 += __shfl_xor(a3, 1);
    a4 += __shfl_xor(a4, 1); a5 += __shfl_xor(a5, 1);
    a6 += __shfl_xor(a6, 1); a7 += __shfl_xor(a7, 1);
    a0 += __shfl_xor(a0, 2); a1 += __shfl_xor(a1, 2);
    a2 += __shfl_xor(a2, 2); a3 += __shfl_xor(a3, 2);
    a4 += __shfl_xor(a4, 2); a5 += __shfl_xor(a5, 2);
    a6 += __shfl_xor(a6, 2); a7 += __shfl_xor(a7, 2);
    if (lead) {
        float h0 = fast_tanh(a0 + (float)base8[0]);
        float h1 = fast_tanh(a1 + (float)base8[1]);
        float h2 = fast_tanh(a2 + (float)base8[2]);
        float h3 = fast_tanh(a3 + (float)base8[3]);
        float h4 = fast_tanh(a4 + (float)base8[4]);
        float h5 = fast_tanh(a5 + (float)base8[5]);
        float h6 = fast_tanh(a6 + (float)base8[6]);
        float h7 = fast_tanh(a7 + (float)base8[7]);
        half8 hh;
        hh[0] = (_Float16)h0; hh[1] = (_Float16)h1;
        hh[2] = (_Float16)h2; hh[3] = (_Float16)h3;
        hh[4] = (_Float16)h4; hh[5] = (_Float16)h5;
        hh[6] = (_Float16)h6; hh[7] = (_Float16)h7;
        h_out[r] = hh;
        __builtin_nontemporal_store(h0, &out[((size_t)0 * TSZ + t) * HSZ + r]);
        __builtin_nontemporal_store(h1, &out[((size_t)1 * TSZ + t) * HSZ + r]);
        __builtin_nontemporal_store(h2, &out[((size_t)2 * TSZ + t) * HSZ + r]);
        __builtin_nontemporal_store(h3, &out[((size_t)3 * TSZ + t) * HSZ + r]);
        __builtin_nontemporal_store(h4, &out[((size_t)4 * TSZ + t) * HSZ + r]);
        __builtin_nontemporal_store(h5, &out[((size_t)5 * TSZ + t) * HSZ + r]);
        __builtin_nontemporal_store(h6, &out[((size_t)6 * TSZ + t) * HSZ + r]);
        __builtin_nontemporal_store(h7, &out[((size_t)7 * TSZ + t) * HSZ + r]);
    }
}

// ---------------- launch ----------------

static inline size_t align256(size_t x) { return (x + 255) & ~(size_t)255; }

extern "C" void kernel_launch(void* const* d_in, const int* in_sizes, int n_in,
                              void* d_out, int out_size, void* d_ws, size_t ws_size,
                              hipStream_t stream) {
    const float* x          = (const float*)d_in[0];
    const float* hh_values  = (const float*)d_in[1];
    const float* hh_bias    = (const float*)d_in[2];
    const float* ih_values  = (const float*)d_in[3];
    const int*   hh_indices = (const int*)d_in[4];
    const int*   ih_indices = (const int*)d_in[5];
    float* out = (float*)d_out;

    char* ws = (char*)d_ws;
    _Float16* X2h   = (_Float16*)ws; ws += align256((size_t)INSZ * 256 * 2);   // 25.6 MB
    half4*  ihcT    = (half4*)ws;  ws += align256((size_t)HSZ * 256 * 2);      // 25.6 MB
    half8*  hbuf    = (half8*)ws;  ws += align256((size_t)2 * HSZ * 16);       // 1.6 MB
    int*    hh_ptr  = (int*)ws;    ws += align256((size_t)(HSZ + 1) * 4);
    int*    ih_ptr  = (int*)ws;    ws += align256((size_t)(HSZ + 1) * 4);
    int*    ghist   = (int*)ws;    ws += align256((size_t)2 * HWORDS * 4);     // 800 KB
    int*    partials= (int*)ws;    ws += align256((size_t)256 * 4);
    int*    cbs     = (int*)ws;    ws += align256((size_t)2 * (NCB + 1) * 4);
    uint2*  tmp_hh  = (uint2*)ws;  ws += align256((size_t)NNZc * 8);           // 6.4 MB
    uint2*  tmp_ih  = (uint2*)ws;  ws += align256((size_t)NNZc * 8);           // 6.4 MB
    unsigned* cv_hh = (unsigned*)ws; ws += align256((size_t)NNZc * 4);         // 3.2 MB
    unsigned* cv_ih = (unsigned*)ws; ws += align256((size_t)NNZc * 4);         // 3.2 MB

    p1_count<<<dim3(NBLK, 2), 256, 0, stream>>>(hh_indices, ih_indices, ghist);
    p2scanA<<<dim3(NC2, 2), 1024, 0, stream>>>(ghist, partials);
    p2scanB<<<1, 128, 0, stream>>>(partials);
    p2scanC<<<dim3((HWORDS + 255) / 256, 2), 256, 0, stream>>>(ghist, partials, cbs);
    p2_part<<<dim3(NBLK, 2), 256, 0, stream>>>(hh_indices, hh_values, ih_indices, ih_values,
                                               ghist, tmp_hh, tmp_ih);
    p3_final<<<dim3(NCB, 2), 256, 0, stream>>>(cbs, tmp_hh, tmp_ih,
                                               hh_ptr, ih_ptr, cv_hh, cv_ih);

    transpose_x2<<<(INSZ + 63) / 64, 256, 64 * 257 * 4, stream>>>(x, X2h);
    ihc_kernel<<<HSZ / 4, 256, 0, stream>>>(ih_ptr, cv_ih, hh_bias, (const half4*)X2h, ihcT);

    int stepBlocks = (4 * HSZ + 255) / 256;
    for (int t = 0; t < TSZ; ++t) {
        half8* hin  = hbuf + (size_t)(t & 1) * HSZ;       // t=0: never read (h0=0 analytic)
        half8* hout = hbuf + (size_t)((t + 1) & 1) * HSZ;
        step_kernel<<<stepBlocks, 256, 0, stream>>>(hh_ptr, cv_hh, (const half8*)ihcT,
                                                    hin, hout, out, t);
    }
}